// Round 3
// baseline (504.568 us; speedup 1.0000x reference)
//
#include <hip/hip_runtime.h>
#include <hip/hip_bf16.h>
#include <math.h>

#define NEG_SLOPE 0.2f

typedef __attribute__((ext_vector_type(8))) short short8;
typedef __attribute__((ext_vector_type(4))) float float4v;

__device__ __forceinline__ unsigned f2bf(float f) {
  unsigned u = __builtin_bit_cast(unsigned, f);
  return (u + 0x7fffu + ((u >> 16) & 1u)) >> 16;  // RNE
}
__device__ __forceinline__ float bflo(unsigned u) {
  return __builtin_bit_cast(float, u << 16);
}
__device__ __forceinline__ float bfhi(unsigned u) {
  return __builtin_bit_cast(float, u & 0xffff0000u);
}
// packed f32x2 -> bf16x2 (RNE, same rounding as f2bf); gfx950 has no builtin
__device__ __forceinline__ unsigned cvtpk(float lo, float hi) {
  unsigned r;
  asm("v_cvt_pk_bf16_f32 %0, %1, %2" : "=v"(r) : "v"(lo), "v"(hi));
  return r;
}
// async global->LDS DMA, 16B per lane; LDS dest = wave-uniform base + lane*16
__device__ __forceinline__ void gl2lds16(const void* g, void* l) {
  __builtin_amdgcn_global_load_lds(
      (const __attribute__((address_space(1))) unsigned*)g,
      (__attribute__((address_space(3))) unsigned*)l, 16, 0, 0);
}

// ---------------- weight pre-transpose: Wt[c][k] bf16, c in [0,256) --------
__global__ __launch_bounds__(256) void convert_w(const float* __restrict__ W1,
                                                 const float* __restrict__ Wp,
                                                 short* __restrict__ Wt) {
  int k = blockIdx.x;   // 0..767
  int c = threadIdx.x;  // 0..255
  float v = (c < 128) ? W1[k * 128 + c] : Wp[k * 128 + (c - 128)];
  Wt[(size_t)c * 768 + k] = (short)f2bf(v);
}

// ------- bf16 MFMA GEMM: emits h1bf (bf16-packed) + proj (fp32) ------------
// BM=64, BN=256, BK=32, 256 thr (4 waves). Waves 0-1: h1 cols -> h1bf pack.
// Waves 2-3: proj cols.
// R6: global_load_lds staging, pre-swizzled source => 2-way conflicts.
// R7: LDS double-buffer + stage-ahead (T3-lite, m248v2 recipe): DMA for tile
// t+1 issued BEFORE computing tile t; the vmcnt(0) drain happens at the
// end-of-iter barrier where it's been covered by ds_read+cvt+MFMA. One
// barrier per K-step. Loop 2x-unrolled so buffer index is compile-time.
__global__ __launch_bounds__(256) void gemm_mfma(const float* __restrict__ x,
                                                 const short* __restrict__ Wt,
                                                 float* __restrict__ proj,
                                                 unsigned* __restrict__ h1bf) {
  __shared__ float As[2][2048];  // [64 rows][32 k] f32, 16B-chunk swizzled
  __shared__ short Bs[2][8192];  // [256 cols][32 k] bf16, 16B-chunk swizzled
  const int tid = threadIdx.x;
  const int w = tid >> 6, l = tid & 63;
  const int l15 = l & 15, l4 = l >> 4;
  const int row0 = blockIdx.x * 64;

  // ---- per-lane staging addresses (swizzle baked into global source) ----
  // A: instr i covers rows w*16+i*8 .. +7, 128B/row, chunk q = (l&7)^(l>>3)
  const char* ag[2];
#pragma unroll
  for (int i = 0; i < 2; i++) {
    int row = w * 16 + i * 8 + (l >> 3);
    int q = (l & 7) ^ (l >> 3);
    ag[i] = (const char*)x + (size_t)(row0 + row) * 3072 + q * 16;
  }
  // B: instr i covers cols w*64+i*16 .. +15, 64B/col, chunk q=(l&3)^((l>>3)&3)
  const char* bg[4];
#pragma unroll
  for (int i = 0; i < 4; i++) {
    int c = w * 64 + i * 16 + (l >> 2);
    int q = (l & 3) ^ ((l >> 3) & 3);
    bg[i] = (const char*)Wt + (size_t)c * 1536 + q * 16;
  }

  float4v acc[4][4] = {};
  const int pc = l4 ^ ((l15 >> 1) & 3);  // B physical chunk for this lane
  const int p0 = (l4 * 2) ^ (l15 & 7);   // A physical chunk (lo)

  // stage tile t into buffer b (6 DMA instructions, no VGPR round-trip)
  auto stage = [&](int b, int t) {
    gl2lds16(ag[0] + t * 128, (char*)As[b] + w * 2048 + 0 * 1024);
    gl2lds16(ag[1] + t * 128, (char*)As[b] + w * 2048 + 1 * 1024);
    gl2lds16(bg[0] + t * 64, (char*)Bs[b] + w * 4096 + 0 * 1024);
    gl2lds16(bg[1] + t * 64, (char*)Bs[b] + w * 4096 + 1 * 1024);
    gl2lds16(bg[2] + t * 64, (char*)Bs[b] + w * 4096 + 2 * 1024);
    gl2lds16(bg[3] + t * 64, (char*)Bs[b] + w * 4096 + 3 * 1024);
  };
  // compute on buffer b
  auto compute = [&](int b) {
    const char* asb = (const char*)As[b];
    const char* bsb = (const char*)Bs[b];
    short8 afr[4];
#pragma unroll
    for (int rt = 0; rt < 4; rt++) {
      const int r = rt * 16 + l15;
      float4 lo = *(const float4*)(asb + r * 128 + p0 * 16);
      float4 hi = *(const float4*)(asb + r * 128 + (p0 ^ 1) * 16);
      uint4 pk;
      pk.x = cvtpk(lo.x, lo.y);
      pk.y = cvtpk(lo.z, lo.w);
      pk.z = cvtpk(hi.x, hi.y);
      pk.w = cvtpk(hi.z, hi.w);
      afr[rt] = __builtin_bit_cast(short8, pk);
    }
#pragma unroll
    for (int ct = 0; ct < 4; ct++) {
      const int c = w * 64 + ct * 16 + l15;
      short8 bfr = *(const short8*)(bsb + c * 64 + pc * 16);
#pragma unroll
      for (int rt = 0; rt < 4; rt++)
        acc[rt][ct] =
            __builtin_amdgcn_mfma_f32_16x16x32_bf16(afr[rt], bfr, acc[rt][ct], 0, 0, 0);
    }
  };

  stage(0, 0);
  __syncthreads();  // tile 0 resident
  for (int t = 0; t < 24; t += 2) {
    stage(1, t + 1);  // issue next tile's DMA (t+1 <= 23 always here)
    compute(0);
    __syncthreads();  // drains vmcnt: tile t+1 resident; buf0 reads done
    if (t + 2 < 24) stage(0, t + 2);
    compute(1);
    __syncthreads();  // drains vmcnt: tile t+2 resident; buf1 reads done
  }

  const int colbase = w * 64;
  if (w < 2) {
    // h1 columns -> packed bf16 (pair channels via 1 shuffle per element)
#pragma unroll
    for (int ct = 0; ct < 4; ct++) {
      const int c = colbase + ct * 16 + l15;
#pragma unroll
      for (int rt = 0; rt < 4; rt++) {
#pragma unroll
        for (int r = 0; r < 4; r++) {
          const int R = row0 + rt * 16 + l4 * 4 + r;
          unsigned u = f2bf(acc[rt][ct][r]);
          unsigned up = __shfl_xor(u, 1);
          if ((l15 & 1) == 0) h1bf[(size_t)R * 64 + (c >> 1)] = u | (up << 16);
        }
      }
    }
  } else {
    // proj columns
#pragma unroll
    for (int ct = 0; ct < 4; ct++) {
      const int c = colbase - 128 + ct * 16 + l15;
#pragma unroll
      for (int rt = 0; rt < 4; rt++) {
#pragma unroll
        for (int r = 0; r < 4; r++) {
          const int R = row0 + rt * 16 + l4 * 4 + r;
          proj[(size_t)R * 128 + c] = acc[rt][ct][r];
        }
      }
    }
  }
}

// ---------------- attention logits from h1bf (thread per node,head) --------
__global__ __launch_bounds__(256) void attn1b(const uint4* __restrict__ h1bf4,
                                              const float* __restrict__ att_src1,
                                              const float* __restrict__ att_dst1,
                                              float* __restrict__ a_s1,
                                              float* __restrict__ a_d1) {
  const int t = blockIdx.x * 256 + threadIdx.x;  // t in [0, N*8)
  const int n = t >> 3, h = t & 7;
  uint4 q0 = h1bf4[(size_t)n * 16 + h * 2];
  uint4 q1 = h1bf4[(size_t)n * 16 + h * 2 + 1];
  float v[16];
  v[0] = bflo(q0.x); v[1] = bfhi(q0.x); v[2] = bflo(q0.y); v[3] = bfhi(q0.y);
  v[4] = bflo(q0.z); v[5] = bfhi(q0.z); v[6] = bflo(q0.w); v[7] = bfhi(q0.w);
  v[8] = bflo(q1.x); v[9] = bfhi(q1.x); v[10] = bflo(q1.y); v[11] = bfhi(q1.y);
  v[12] = bflo(q1.z); v[13] = bfhi(q1.z); v[14] = bflo(q1.w); v[15] = bfhi(q1.w);
  float as = 0.f, ad = 0.f;
#pragma unroll
  for (int i = 0; i < 16; i++) {
    as += v[i] * att_src1[h * 16 + i];
    ad += v[i] * att_dst1[h * 16 + i];
  }
  a_s1[t] = as;
  a_d1[t] = ad;
}

// ---------------- counting sort of edges by dst ----------------------------
__global__ void init_counts(int* counts, int N) {
  int i = blockIdx.x * blockDim.x + threadIdx.x;
  if (i < N) counts[i] = 1;  // self loop
}

// rank = atomicAdd return (was previously discarded) so scatter needs no atomics
__global__ void hist_kernel(const int* __restrict__ dst, int* counts,
                            int* __restrict__ rank, int E) {
  int i = blockIdx.x * blockDim.x + threadIdx.x;
  int base = i * 4;
  if (base + 3 < E) {
    int4 d = *(const int4*)&dst[base];
    int4 r;
    r.x = atomicAdd(&counts[d.x], 1);
    r.y = atomicAdd(&counts[d.y], 1);
    r.z = atomicAdd(&counts[d.z], 1);
    r.w = atomicAdd(&counts[d.w], 1);
    *(int4*)&rank[base] = r;
  } else {
    for (int j = base; j < E; j++) rank[j] = atomicAdd(&counts[dst[j]], 1);
  }
}

__global__ __launch_bounds__(256) void scan_a(const int* __restrict__ counts,
                                              int* offsets, int* bsum) {
  __shared__ int s[256];
  int t = threadIdx.x, idx = blockIdx.x * 256 + t;
  int v = counts[idx];
  s[t] = v;
  __syncthreads();
  for (int d = 1; d < 256; d <<= 1) {
    int x = (t >= d) ? s[t - d] : 0;
    __syncthreads();
    s[t] += x;
    __syncthreads();
  }
  offsets[idx] = s[t] - v;
  if (t == 255) bsum[blockIdx.x] = s[t];
}

__global__ __launch_bounds__(256) void scan_b(int* bsum) {
  __shared__ int s[256];
  int t = threadIdx.x;
  int v = bsum[t];
  s[t] = v;
  __syncthreads();
  for (int d = 1; d < 256; d <<= 1) {
    int x = (t >= d) ? s[t - d] : 0;
    __syncthreads();
    s[t] += x;
    __syncthreads();
  }
  bsum[t] = s[t] - v;
}

// also places the self-loop at segment start
__global__ __launch_bounds__(256) void scan_c(int* offsets, const int* bsum,
                                              int* sortedsrc, int N, int Etot) {
  int t = threadIdx.x, idx = blockIdx.x * 256 + t;
  int off = offsets[idx] + bsum[blockIdx.x];
  offsets[idx] = off;
  sortedsrc[off] = idx;  // self loop at slot 0 (ranks from hist start at 1)
  if (idx == 0) offsets[N] = Etot;
}

// atomic-free scatter — slot = offsets[dst] + rank (rank >= 1).
__global__ void scatter_edges(const int* __restrict__ src,
                              const int* __restrict__ dst,
                              const int* __restrict__ rank,
                              const int* __restrict__ offsets,
                              int* __restrict__ sortedsrc, int E) {
  int i = blockIdx.x * blockDim.x + threadIdx.x;
  int base = i * 4;
  if (base + 3 < E) {
    int4 s = *(const int4*)&src[base];
    int4 d = *(const int4*)&dst[base];
    int4 r = *(const int4*)&rank[base];
    sortedsrc[offsets[d.x] + r.x] = s.x;
    sortedsrc[offsets[d.y] + r.y] = s.y;
    sortedsrc[offsets[d.z] + r.z] = s.z;
    sortedsrc[offsets[d.w] + r.w] = s.w;
  } else {
    for (int j = base; j < E; j++)
      sortedsrc[offsets[dst[j]] + rank[j]] = src[j];
  }
}

// ------- layer-1 aggregation + residual + ELU + layer-2 features -----------
// 16 nodes/block (256 thr), 16 lanes/node, 8 channels/lane (uint4 gathers),
// 4-deep edge pipeline.
__global__ __launch_bounds__(256) void agg1_fused(
    const uint4* __restrict__ h1bf4, const float* __restrict__ proj,
    const float* __restrict__ a_s1, const float* __restrict__ a_d1,
    const int* __restrict__ offsets, const int* __restrict__ sortedsrc,
    const float* __restrict__ b1, const float* __restrict__ bp,
    const float* __restrict__ W2, const float* __restrict__ att_s2,
    const float* __restrict__ att_d2, float* __restrict__ h2,
    float* __restrict__ as2, float* __restrict__ ad2) {
  const int t = threadIdx.x;
  const int n = blockIdx.x * 16 + (t >> 4);
  const int k = t & 15;   // lane within node: channels 8k..8k+7
  const int hd = k >> 1;  // head
  const float ad = a_d1[n * 8 + hd];
  const int begin = offsets[n], end = offsets[n + 1];
  float acc[8] = {};
  float aw = 0.f;
  int j = begin;
  for (; j + 4 <= end; j += 4) {
    int s0 = sortedsrc[j], s1 = sortedsrc[j + 1];
    int s2 = sortedsrc[j + 2], s3 = sortedsrc[j + 3];
    float e0 = a_s1[s0 * 8 + hd], e1 = a_s1[s1 * 8 + hd];
    float e2 = a_s1[s2 * 8 + hd], e3 = a_s1[s3 * 8 + hd];
    uint4 q0 = h1bf4[(size_t)s0 * 16 + k];
    uint4 q1 = h1bf4[(size_t)s1 * 16 + k];
    uint4 q2 = h1bf4[(size_t)s2 * 16 + k];
    uint4 q3 = h1bf4[(size_t)s3 * 16 + k];
    e0 += ad; e1 += ad; e2 += ad; e3 += ad;
    float w0 = __expf(e0 > 0.f ? e0 : NEG_SLOPE * e0);
    float w1 = __expf(e1 > 0.f ? e1 : NEG_SLOPE * e1);
    float w2 = __expf(e2 > 0.f ? e2 : NEG_SLOPE * e2);
    float w3 = __expf(e3 > 0.f ? e3 : NEG_SLOPE * e3);
    acc[0] += w0 * bflo(q0.x) + w1 * bflo(q1.x) + w2 * bflo(q2.x) + w3 * bflo(q3.x);
    acc[1] += w0 * bfhi(q0.x) + w1 * bfhi(q1.x) + w2 * bfhi(q2.x) + w3 * bfhi(q3.x);
    acc[2] += w0 * bflo(q0.y) + w1 * bflo(q1.y) + w2 * bflo(q2.y) + w3 * bflo(q3.y);
    acc[3] += w0 * bfhi(q0.y) + w1 * bfhi(q1.y) + w2 * bfhi(q2.y) + w3 * bfhi(q3.y);
    acc[4] += w0 * bflo(q0.z) + w1 * bflo(q1.z) + w2 * bflo(q2.z) + w3 * bflo(q3.z);
    acc[5] += w0 * bfhi(q0.z) + w1 * bfhi(q1.z) + w2 * bfhi(q2.z) + w3 * bfhi(q3.z);
    acc[6] += w0 * bflo(q0.w) + w1 * bflo(q1.w) + w2 * bflo(q2.w) + w3 * bflo(q3.w);
    acc[7] += w0 * bfhi(q0.w) + w1 * bfhi(q1.w) + w2 * bfhi(q2.w) + w3 * bfhi(q3.w);
    aw += (w0 + w1) + (w2 + w3);
  }
  for (; j < end; j++) {
    int s0 = sortedsrc[j];
    float e0 = a_s1[s0 * 8 + hd] + ad;
    uint4 q0 = h1bf4[(size_t)s0 * 16 + k];
    float w0 = __expf(e0 > 0.f ? e0 : NEG_SLOPE * e0);
    acc[0] += w0 * bflo(q0.x);
    acc[1] += w0 * bfhi(q0.x);
    acc[2] += w0 * bflo(q0.y);
    acc[3] += w0 * bfhi(q0.y);
    acc[4] += w0 * bflo(q0.z);
    acc[5] += w0 * bfhi(q0.z);
    acc[6] += w0 * bflo(q0.w);
    acc[7] += w0 * bfhi(q0.w);
    aw += w0;
  }
  const float inv = 1.f / (aw + 1e-16f);
  const float4 pj0 = *(const float4*)&proj[(size_t)n * 128 + k * 8];
  const float4 pj1 = *(const float4*)&proj[(size_t)n * 128 + k * 8 + 4];
  const float4 b1a = *(const float4*)&b1[k * 8];
  const float4 b1b = *(const float4*)&b1[k * 8 + 4];
  const float4 bpa = *(const float4*)&bp[k * 8];
  const float4 bpb = *(const float4*)&bp[k * 8 + 4];
  float v[8];
  v[0] = acc[0] * inv + pj0.x + b1a.x + bpa.x;
  v[1] = acc[1] * inv + pj0.y + b1a.y + bpa.y;
  v[2] = acc[2] * inv + pj0.z + b1a.z + bpa.z;
  v[3] = acc[3] * inv + pj0.w + b1a.w + bpa.w;
  v[4] = acc[4] * inv + pj1.x + b1b.x + bpb.x;
  v[5] = acc[5] * inv + pj1.y + b1b.y + bpb.y;
  v[6] = acc[6] * inv + pj1.z + b1b.z + bpb.z;
  v[7] = acc[7] * inv + pj1.w + b1b.w + bpb.w;
  float p0 = 0.f, p1 = 0.f;
#pragma unroll
  for (int i = 0; i < 8; i++) {
    float vi = v[i] > 0.f ? v[i] : (__expf(v[i]) - 1.f);
    float2 w2 = *(const float2*)&W2[(k * 8 + i) * 2];
    p0 += vi * w2.x;
    p1 += vi * w2.y;
  }
#pragma unroll
  for (int off = 8; off; off >>= 1) {
    p0 += __shfl_xor(p0, off);
    p1 += __shfl_xor(p1, off);
  }
  if (k == 0) {
    h2[2 * n] = p0;
    h2[2 * n + 1] = p1;
    as2[n] = p0 * att_s2[0] + p1 * att_s2[1];
    ad2[n] = p0 * att_d2[0] + p1 * att_d2[1];
  }
}

// ---------------- layer-2 aggregation (16 lanes per node) ------------------
__global__ __launch_bounds__(256) void agg2(
    const float* __restrict__ h2, const float* __restrict__ as2,
    const float* __restrict__ ad2, const int* __restrict__ offsets,
    const int* __restrict__ sortedsrc, const float* __restrict__ b2,
    float* __restrict__ out, int N) {
  const int node = blockIdx.x * 16 + (threadIdx.x >> 4);
  const int lane = threadIdx.x & 15;
  const int begin = offsets[node], end = offsets[node + 1];
  const float ad = ad2[node];
  float acc0 = 0.f, acc1 = 0.f, aw = 0.f;
  for (int j = begin + lane; j < end; j += 16) {
    int s = sortedsrc[j];
    float e = as2[s] + ad;
    float w = __expf(e > 0.f ? e : NEG_SLOPE * e);
    float2 hh = *(const float2*)&h2[2 * s];
    acc0 += w * hh.x;
    acc1 += w * hh.y;
    aw += w;
  }
#pragma unroll
  for (int off = 8; off; off >>= 1) {
    acc0 += __shfl_xor(acc0, off);
    acc1 += __shfl_xor(acc1, off);
    aw += __shfl_xor(aw, off);
  }
  if (lane == 0) {
    float inv = 1.f / (aw + 1e-16f);
    out[2 * node] = acc0 * inv + b2[0];
    out[2 * node + 1] = acc1 * inv + b2[1];
  }
}

extern "C" void kernel_launch(void* const* d_in, const int* in_sizes, int n_in,
                              void* d_out, int out_size, void* d_ws,
                              size_t ws_size, hipStream_t stream) {
  const float* x = (const float*)d_in[0];
  const int* edge_index = (const int*)d_in[1];
  const float* W1 = (const float*)d_in[2];
  const float* att_src1 = (const float*)d_in[3];
  const float* att_dst1 = (const float*)d_in[4];
  const float* b1 = (const float*)d_in[5];
  const float* Wp = (const float*)d_in[6];
  const float* bp = (const float*)d_in[7];
  const float* W2 = (const float*)d_in[8];
  const float* att_src2 = (const float*)d_in[9];
  const float* att_dst2 = (const float*)d_in[10];
  const float* b2 = (const float*)d_in[11];
  float* out = (float*)d_out;

  const int N = in_sizes[0] / 768;
  const int E = in_sizes[1] / 2;
  const int Etot = E + N;
  const int* src = edge_index;
  const int* dst = edge_index + E;

  char* ws = (char*)d_ws;
  size_t off = 0;
  auto alloc = [&](size_t bytes) {
    size_t cur = off;
    off += (bytes + 255) & ~(size_t)255;
    return (void*)(ws + cur);
  };
  float* proj = (float*)alloc((size_t)N * 128 * 4);
  unsigned* h1bf = (unsigned*)alloc((size_t)N * 64 * 4);
  float* a_s1 = (float*)alloc((size_t)N * 8 * 4);
  float* a_d1 = (float*)alloc((size_t)N * 8 * 4);
  float* h2 = (float*)alloc((size_t)N * 2 * 4);
  float* as2 = (float*)alloc((size_t)N * 4);
  float* ad2 = (float*)alloc((size_t)N * 4);
  int* counts = (int*)alloc((size_t)N * 4);
  int* offsets = (int*)alloc(((size_t)N + 1) * 4);
  int* rank = (int*)alloc((size_t)E * 4);
  int* bsum = (int*)alloc(256 * 4);
  int* sortedsrc = (int*)alloc((size_t)Etot * 4);
  short* Wt = (short*)alloc((size_t)256 * 768 * 2);

  // 0. weights -> bf16 B^T
  convert_w<<<768, 256, 0, stream>>>(W1, Wp, Wt);
  // 1. MFMA GEMM (emits h1bf + proj)
  gemm_mfma<<<N / 64, 256, 0, stream>>>(x, Wt, proj, h1bf);
  // 2. attention logits from h1bf
  attn1b<<<N * 8 / 256, 256, 0, stream>>>((const uint4*)h1bf, att_src1,
                                          att_dst1, a_s1, a_d1);
  // 3. counting sort by dst (self loop placed in scan_c; rank from hist)
  init_counts<<<(N + 255) / 256, 256, 0, stream>>>(counts, N);
  hist_kernel<<<(E / 4 + 255) / 256, 256, 0, stream>>>(dst, counts, rank, E);
  scan_a<<<N / 256, 256, 0, stream>>>(counts, offsets, bsum);
  scan_b<<<1, 256, 0, stream>>>(bsum);
  scan_c<<<N / 256, 256, 0, stream>>>(offsets, bsum, sortedsrc, N, Etot);
  scatter_edges<<<(E / 4 + 255) / 256, 256, 0, stream>>>(src, dst, rank,
                                                         offsets, sortedsrc, E);
  // 4. layer-1 aggregation + residual + ELU + layer-2 features (fused)
  agg1_fused<<<N / 16, 256, 0, stream>>>((const uint4*)h1bf, proj, a_s1, a_d1,
                                         offsets, sortedsrc, b1, bp, W2,
                                         att_src2, att_dst2, h2, as2, ad2);
  // 5. layer-2 aggregation -> output
  agg2<<<N / 16, 256, 0, stream>>>(h2, as2, ad2, offsets, sortedsrc, b2, out,
                                   N);
}

// Round 5
// 500.880 us; speedup vs baseline: 1.0074x; 1.0074x over previous
//
#include <hip/hip_runtime.h>
#include <hip/hip_bf16.h>
#include <math.h>

#define NEG_SLOPE 0.2f

typedef __attribute__((ext_vector_type(8))) short short8;
typedef __attribute__((ext_vector_type(4))) float float4v;

__device__ __forceinline__ unsigned f2bf(float f) {
  unsigned u = __builtin_bit_cast(unsigned, f);
  return (u + 0x7fffu + ((u >> 16) & 1u)) >> 16;  // RNE
}
__device__ __forceinline__ float bflo(unsigned u) {
  return __builtin_bit_cast(float, u << 16);
}
__device__ __forceinline__ float bfhi(unsigned u) {
  return __builtin_bit_cast(float, u & 0xffff0000u);
}
// packed f32x2 -> bf16x2 (RNE, same rounding as f2bf); gfx950 has no builtin
__device__ __forceinline__ unsigned cvtpk(float lo, float hi) {
  unsigned r;
  asm("v_cvt_pk_bf16_f32 %0, %1, %2" : "=v"(r) : "v"(lo), "v"(hi));
  return r;
}
// async global->LDS DMA, 16B per lane; LDS dest = wave-uniform base + lane*16
__device__ __forceinline__ void gl2lds16(const void* g, void* l) {
  __builtin_amdgcn_global_load_lds(
      (const __attribute__((address_space(1))) unsigned*)g,
      (__attribute__((address_space(3))) unsigned*)l, 16, 0, 0);
}

// ---------------- weight pre-transpose: Wt[c][k] bf16, c in [0,256) --------
__global__ __launch_bounds__(256) void convert_w(const float* __restrict__ W1,
                                                 const float* __restrict__ Wp,
                                                 short* __restrict__ Wt) {
  int k = blockIdx.x;   // 0..767
  int c = threadIdx.x;  // 0..255
  float v = (c < 128) ? W1[k * 128 + c] : Wp[k * 128 + (c - 128)];
  Wt[(size_t)c * 768 + k] = (short)f2bf(v);
}

// ------- bf16 MFMA GEMM: emits h1bf (bf16-packed) + proj (fp32) ------------
// BM=64, BN=256, BK=32, 256 thr (4 waves). Waves 0-1: h1 cols -> h1bf pack.
// Waves 2-3: proj cols.
// R6: global_load_lds staging for B, pre-swizzled source => ~2-way conflicts.
// R7: LDS double-buffer + stage-ahead (neutral — drain wasn't critical path).
// R8: occupancy fix. R7's 48KB LDS capped residency at 3 blocks/CU vs a
// 4-block/CU grid => 1-block tail, avg occupancy ~20%. A is now reg-staged
// as bf16 (float4x2 -> cvt_pk -> one swizzled ds_write_b128/thread):
// LDS = 2*(4K+16K) = 40960B => exactly 4 blocks/CU, no tail. Also cuts
// fragment reads 12->8 b128/thread/K-step and removes cvt from compute.
// R9: identical resubmit (R8 bench died to container infra, no measurement).
__global__ __launch_bounds__(256, 4) void gemm_mfma(
    const float* __restrict__ x, const short* __restrict__ Wt,
    float* __restrict__ proj, unsigned* __restrict__ h1bf) {
  __shared__ short As[2][2048];  // [64 rows][32 k] bf16, 16B-slot swizzled
  __shared__ short Bs[2][8192];  // [256 cols][32 k] bf16, 16B-slot swizzled
  const int tid = threadIdx.x;
  const int w = tid >> 6, l = tid & 63;
  const int l15 = l & 15, l4 = l >> 4;
  const int row0 = blockIdx.x * 64;

  // ---- A reg-staging: thread t covers row t>>2, k-chunk t&3 (8 k-values) --
  // swizzle: phys_chunk = chunk ^ ((row>>1)&3)  (2-way max on write & read)
  const float* xsrc = x + (size_t)(row0 + (tid >> 2)) * 768 + (tid & 3) * 8;
  const int awoff = (tid >> 2) * 64 + (((tid & 3) ^ ((tid >> 3) & 3)) << 4);
  // fragment read offset: row l15 (+rt*16), logical chunk l4
  const int aoff = l15 * 64 + ((l4 ^ ((l15 >> 1) & 3)) << 4);

  // ---- B DMA staging (swizzle baked into global source) ------------------
  // instr i covers cols w*64+i*16 .. +15, 64B/col, chunk q=(l&3)^((l>>3)&3)
  const char* bg[4];
#pragma unroll
  for (int i = 0; i < 4; i++) {
    int c = w * 64 + i * 16 + (l >> 2);
    int q = (l & 3) ^ ((l >> 3) & 3);
    bg[i] = (const char*)Wt + (size_t)c * 1536 + q * 16;
  }
  const int pc = l4 ^ ((l15 >> 1) & 3);  // B physical chunk for this lane

  float4v acc[4][4] = {};

  auto loadA = [&](int t, float4& r0, float4& r1) {
    const float* p = xsrc + t * 32;
    r0 = *(const float4*)p;
    r1 = *(const float4*)(p + 4);
  };
  auto writeA = [&](short* asb, const float4& r0, const float4& r1) {
    uint4 pk;
    pk.x = cvtpk(r0.x, r0.y);
    pk.y = cvtpk(r0.z, r0.w);
    pk.z = cvtpk(r1.x, r1.y);
    pk.w = cvtpk(r1.z, r1.w);
    *(uint4*)((char*)asb + awoff) = pk;
  };
  auto stageB = [&](short* bsb, int t) {
    gl2lds16(bg[0] + t * 64, (char*)bsb + w * 4096 + 0 * 1024);
    gl2lds16(bg[1] + t * 64, (char*)bsb + w * 4096 + 1 * 1024);
    gl2lds16(bg[2] + t * 64, (char*)bsb + w * 4096 + 2 * 1024);
    gl2lds16(bg[3] + t * 64, (char*)bsb + w * 4096 + 3 * 1024);
  };
  auto compute = [&](const short* asb, const short* bsb) {
    short8 afr[4];
#pragma unroll
    for (int rt = 0; rt < 4; rt++)
      afr[rt] = *(const short8*)((const char*)asb + rt * 1024 + aoff);
#pragma unroll
    for (int ct = 0; ct < 4; ct++) {
      short8 bfr =
          *(const short8*)((const char*)bsb + (w * 64 + ct * 16 + l15) * 64 + pc * 16);
#pragma unroll
      for (int rt = 0; rt < 4; rt++)
        acc[rt][ct] =
            __builtin_amdgcn_mfma_f32_16x16x32_bf16(afr[rt], bfr, acc[rt][ct], 0, 0, 0);
    }
  };

  float4 r0, r1;
  loadA(0, r0, r1);
  stageB(Bs[0], 0);
  writeA(As[0], r0, r1);
  __syncthreads();  // tile 0 resident (ds_write lgkm + DMA vmcnt drained)
  for (int t = 0; t < 24; t += 2) {
    loadA(t + 1, r0, r1);   // x loads first: cvt waits only on these
    stageB(Bs[1], t + 1);   // B DMA in flight across compute
    compute(As[0], Bs[0]);
    writeA(As[1], r0, r1);
    __syncthreads();  // tile t+1 resident; buf0 reads done
    if (t + 2 < 24) {
      loadA(t + 2, r0, r1);
      stageB(Bs[0], t + 2);
    }
    compute(As[1], Bs[1]);
    if (t + 2 < 24) writeA(As[0], r0, r1);
    __syncthreads();  // tile t+2 resident; buf1 reads done
  }

  const int colbase = w * 64;
  if (w < 2) {
    // h1 columns -> packed bf16 (pair channels via 1 shuffle per element)
#pragma unroll
    for (int ct = 0; ct < 4; ct++) {
      const int c = colbase + ct * 16 + l15;
#pragma unroll
      for (int rt = 0; rt < 4; rt++) {
#pragma unroll
        for (int r = 0; r < 4; r++) {
          const int R = row0 + rt * 16 + l4 * 4 + r;
          unsigned u = f2bf(acc[rt][ct][r]);
          unsigned up = __shfl_xor(u, 1);
          if ((l15 & 1) == 0) h1bf[(size_t)R * 64 + (c >> 1)] = u | (up << 16);
        }
      }
    }
  } else {
    // proj columns
#pragma unroll
    for (int ct = 0; ct < 4; ct++) {
      const int c = colbase - 128 + ct * 16 + l15;
#pragma unroll
      for (int rt = 0; rt < 4; rt++) {
#pragma unroll
        for (int r = 0; r < 4; r++) {
          const int R = row0 + rt * 16 + l4 * 4 + r;
          proj[(size_t)R * 128 + c] = acc[rt][ct][r];
        }
      }
    }
  }
}

// ---------------- attention logits from h1bf (thread per node,head) --------
__global__ __launch_bounds__(256) void attn1b(const uint4* __restrict__ h1bf4,
                                              const float* __restrict__ att_src1,
                                              const float* __restrict__ att_dst1,
                                              float* __restrict__ a_s1,
                                              float* __restrict__ a_d1) {
  const int t = blockIdx.x * 256 + threadIdx.x;  // t in [0, N*8)
  const int n = t >> 3, h = t & 7;
  uint4 q0 = h1bf4[(size_t)n * 16 + h * 2];
  uint4 q1 = h1bf4[(size_t)n * 16 + h * 2 + 1];
  float v[16];
  v[0] = bflo(q0.x); v[1] = bfhi(q0.x); v[2] = bflo(q0.y); v[3] = bfhi(q0.y);
  v[4] = bflo(q0.z); v[5] = bfhi(q0.z); v[6] = bflo(q0.w); v[7] = bfhi(q0.w);
  v[8] = bflo(q1.x); v[9] = bfhi(q1.x); v[10] = bflo(q1.y); v[11] = bfhi(q1.y);
  v[12] = bflo(q1.z); v[13] = bfhi(q1.z); v[14] = bflo(q1.w); v[15] = bfhi(q1.w);
  float as = 0.f, ad = 0.f;
#pragma unroll
  for (int i = 0; i < 16; i++) {
    as += v[i] * att_src1[h * 16 + i];
    ad += v[i] * att_dst1[h * 16 + i];
  }
  a_s1[t] = as;
  a_d1[t] = ad;
}

// ---------------- counting sort of edges by dst ----------------------------
__global__ void init_counts(int* counts, int N) {
  int i = blockIdx.x * blockDim.x + threadIdx.x;
  if (i < N) counts[i] = 1;  // self loop
}

// rank = atomicAdd return (was previously discarded) so scatter needs no atomics
__global__ void hist_kernel(const int* __restrict__ dst, int* counts,
                            int* __restrict__ rank, int E) {
  int i = blockIdx.x * blockDim.x + threadIdx.x;
  int base = i * 4;
  if (base + 3 < E) {
    int4 d = *(const int4*)&dst[base];
    int4 r;
    r.x = atomicAdd(&counts[d.x], 1);
    r.y = atomicAdd(&counts[d.y], 1);
    r.z = atomicAdd(&counts[d.z], 1);
    r.w = atomicAdd(&counts[d.w], 1);
    *(int4*)&rank[base] = r;
  } else {
    for (int j = base; j < E; j++) rank[j] = atomicAdd(&counts[dst[j]], 1);
  }
}

__global__ __launch_bounds__(256) void scan_a(const int* __restrict__ counts,
                                              int* offsets, int* bsum) {
  __shared__ int s[256];
  int t = threadIdx.x, idx = blockIdx.x * 256 + t;
  int v = counts[idx];
  s[t] = v;
  __syncthreads();
  for (int d = 1; d < 256; d <<= 1) {
    int x = (t >= d) ? s[t - d] : 0;
    __syncthreads();
    s[t] += x;
    __syncthreads();
  }
  offsets[idx] = s[t] - v;
  if (t == 255) bsum[blockIdx.x] = s[t];
}

__global__ __launch_bounds__(256) void scan_b(int* bsum) {
  __shared__ int s[256];
  int t = threadIdx.x;
  int v = bsum[t];
  s[t] = v;
  __syncthreads();
  for (int d = 1; d < 256; d <<= 1) {
    int x = (t >= d) ? s[t - d] : 0;
    __syncthreads();
    s[t] += x;
    __syncthreads();
  }
  bsum[t] = s[t] - v;
}

// also places the self-loop at segment start
__global__ __launch_bounds__(256) void scan_c(int* offsets, const int* bsum,
                                              int* sortedsrc, int N, int Etot) {
  int t = threadIdx.x, idx = blockIdx.x * 256 + t;
  int off = offsets[idx] + bsum[blockIdx.x];
  offsets[idx] = off;
  sortedsrc[off] = idx;  // self loop at slot 0 (ranks from hist start at 1)
  if (idx == 0) offsets[N] = Etot;
}

// atomic-free scatter — slot = offsets[dst] + rank (rank >= 1).
__global__ void scatter_edges(const int* __restrict__ src,
                              const int* __restrict__ dst,
                              const int* __restrict__ rank,
                              const int* __restrict__ offsets,
                              int* __restrict__ sortedsrc, int E) {
  int i = blockIdx.x * blockDim.x + threadIdx.x;
  int base = i * 4;
  if (base + 3 < E) {
    int4 s = *(const int4*)&src[base];
    int4 d = *(const int4*)&dst[base];
    int4 r = *(const int4*)&rank[base];
    sortedsrc[offsets[d.x] + r.x] = s.x;
    sortedsrc[offsets[d.y] + r.y] = s.y;
    sortedsrc[offsets[d.z] + r.z] = s.z;
    sortedsrc[offsets[d.w] + r.w] = s.w;
  } else {
    for (int j = base; j < E; j++)
      sortedsrc[offsets[dst[j]] + rank[j]] = src[j];
  }
}

// ------- layer-1 aggregation + residual + ELU + layer-2 features -----------
// 16 nodes/block (256 thr), 16 lanes/node, 8 channels/lane (uint4 gathers),
// 4-deep edge pipeline.
__global__ __launch_bounds__(256) void agg1_fused(
    const uint4* __restrict__ h1bf4, const float* __restrict__ proj,
    const float* __restrict__ a_s1, const float* __restrict__ a_d1,
    const int* __restrict__ offsets, const int* __restrict__ sortedsrc,
    const float* __restrict__ b1, const float* __restrict__ bp,
    const float* __restrict__ W2, const float* __restrict__ att_s2,
    const float* __restrict__ att_d2, float* __restrict__ h2,
    float* __restrict__ as2, float* __restrict__ ad2) {
  const int t = threadIdx.x;
  const int n = blockIdx.x * 16 + (t >> 4);
  const int k = t & 15;   // lane within node: channels 8k..8k+7
  const int hd = k >> 1;  // head
  const float ad = a_d1[n * 8 + hd];
  const int begin = offsets[n], end = offsets[n + 1];
  float acc[8] = {};
  float aw = 0.f;
  int j = begin;
  for (; j + 4 <= end; j += 4) {
    int s0 = sortedsrc[j], s1 = sortedsrc[j + 1];
    int s2 = sortedsrc[j + 2], s3 = sortedsrc[j + 3];
    float e0 = a_s1[s0 * 8 + hd], e1 = a_s1[s1 * 8 + hd];
    float e2 = a_s1[s2 * 8 + hd], e3 = a_s1[s3 * 8 + hd];
    uint4 q0 = h1bf4[(size_t)s0 * 16 + k];
    uint4 q1 = h1bf4[(size_t)s1 * 16 + k];
    uint4 q2 = h1bf4[(size_t)s2 * 16 + k];
    uint4 q3 = h1bf4[(size_t)s3 * 16 + k];
    e0 += ad; e1 += ad; e2 += ad; e3 += ad;
    float w0 = __expf(e0 > 0.f ? e0 : NEG_SLOPE * e0);
    float w1 = __expf(e1 > 0.f ? e1 : NEG_SLOPE * e1);
    float w2 = __expf(e2 > 0.f ? e2 : NEG_SLOPE * e2);
    float w3 = __expf(e3 > 0.f ? e3 : NEG_SLOPE * e3);
    acc[0] += w0 * bflo(q0.x) + w1 * bflo(q1.x) + w2 * bflo(q2.x) + w3 * bflo(q3.x);
    acc[1] += w0 * bfhi(q0.x) + w1 * bfhi(q1.x) + w2 * bfhi(q2.x) + w3 * bfhi(q3.x);
    acc[2] += w0 * bflo(q0.y) + w1 * bflo(q1.y) + w2 * bflo(q2.y) + w3 * bflo(q3.y);
    acc[3] += w0 * bfhi(q0.y) + w1 * bfhi(q1.y) + w2 * bfhi(q2.y) + w3 * bfhi(q3.y);
    acc[4] += w0 * bflo(q0.z) + w1 * bflo(q1.z) + w2 * bflo(q2.z) + w3 * bflo(q3.z);
    acc[5] += w0 * bfhi(q0.z) + w1 * bfhi(q1.z) + w2 * bfhi(q2.z) + w3 * bfhi(q3.z);
    acc[6] += w0 * bflo(q0.w) + w1 * bflo(q1.w) + w2 * bflo(q2.w) + w3 * bflo(q3.w);
    acc[7] += w0 * bfhi(q0.w) + w1 * bfhi(q1.w) + w2 * bfhi(q2.w) + w3 * bfhi(q3.w);
    aw += (w0 + w1) + (w2 + w3);
  }
  for (; j < end; j++) {
    int s0 = sortedsrc[j];
    float e0 = a_s1[s0 * 8 + hd] + ad;
    uint4 q0 = h1bf4[(size_t)s0 * 16 + k];
    float w0 = __expf(e0 > 0.f ? e0 : NEG_SLOPE * e0);
    acc[0] += w0 * bflo(q0.x);
    acc[1] += w0 * bfhi(q0.x);
    acc[2] += w0 * bflo(q0.y);
    acc[3] += w0 * bfhi(q0.y);
    acc[4] += w0 * bflo(q0.z);
    acc[5] += w0 * bfhi(q0.z);
    acc[6] += w0 * bflo(q0.w);
    acc[7] += w0 * bfhi(q0.w);
    aw += w0;
  }
  const float inv = 1.f / (aw + 1e-16f);
  const float4 pj0 = *(const float4*)&proj[(size_t)n * 128 + k * 8];
  const float4 pj1 = *(const float4*)&proj[(size_t)n * 128 + k * 8 + 4];
  const float4 b1a = *(const float4*)&b1[k * 8];
  const float4 b1b = *(const float4*)&b1[k * 8 + 4];
  const float4 bpa = *(const float4*)&bp[k * 8];
  const float4 bpb = *(const float4*)&bp[k * 8 + 4];
  float v[8];
  v[0] = acc[0] * inv + pj0.x + b1a.x + bpa.x;
  v[1] = acc[1] * inv + pj0.y + b1a.y + bpa.y;
  v[2] = acc[2] * inv + pj0.z + b1a.z + bpa.z;
  v[3] = acc[3] * inv + pj0.w + b1a.w + bpa.w;
  v[4] = acc[4] * inv + pj1.x + b1b.x + bpb.x;
  v[5] = acc[5] * inv + pj1.y + b1b.y + bpb.y;
  v[6] = acc[6] * inv + pj1.z + b1b.z + bpb.z;
  v[7] = acc[7] * inv + pj1.w + b1b.w + bpb.w;
  float p0 = 0.f, p1 = 0.f;
#pragma unroll
  for (int i = 0; i < 8; i++) {
    float vi = v[i] > 0.f ? v[i] : (__expf(v[i]) - 1.f);
    float2 w2 = *(const float2*)&W2[(k * 8 + i) * 2];
    p0 += vi * w2.x;
    p1 += vi * w2.y;
  }
#pragma unroll
  for (int off = 8; off; off >>= 1) {
    p0 += __shfl_xor(p0, off);
    p1 += __shfl_xor(p1, off);
  }
  if (k == 0) {
    h2[2 * n] = p0;
    h2[2 * n + 1] = p1;
    as2[n] = p0 * att_s2[0] + p1 * att_s2[1];
    ad2[n] = p0 * att_d2[0] + p1 * att_d2[1];
  }
}

// ---------------- layer-2 aggregation (16 lanes per node) ------------------
__global__ __launch_bounds__(256) void agg2(
    const float* __restrict__ h2, const float* __restrict__ as2,
    const float* __restrict__ ad2, const int* __restrict__ offsets,
    const int* __restrict__ sortedsrc, const float* __restrict__ b2,
    float* __restrict__ out, int N) {
  const int node = blockIdx.x * 16 + (threadIdx.x >> 4);
  const int lane = threadIdx.x & 15;
  const int begin = offsets[node], end = offsets[node + 1];
  const float ad = ad2[node];
  float acc0 = 0.f, acc1 = 0.f, aw = 0.f;
  for (int j = begin + lane; j < end; j += 16) {
    int s = sortedsrc[j];
    float e = as2[s] + ad;
    float w = __expf(e > 0.f ? e : NEG_SLOPE * e);
    float2 hh = *(const float2*)&h2[2 * s];
    acc0 += w * hh.x;
    acc1 += w * hh.y;
    aw += w;
  }
#pragma unroll
  for (int off = 8; off; off >>= 1) {
    acc0 += __shfl_xor(acc0, off);
    acc1 += __shfl_xor(acc1, off);
    aw += __shfl_xor(aw, off);
  }
  if (lane == 0) {
    float inv = 1.f / (aw + 1e-16f);
    out[2 * node] = acc0 * inv + b2[0];
    out[2 * node + 1] = acc1 * inv + b2[1];
  }
}

extern "C" void kernel_launch(void* const* d_in, const int* in_sizes, int n_in,
                              void* d_out, int out_size, void* d_ws,
                              size_t ws_size, hipStream_t stream) {
  const float* x = (const float*)d_in[0];
  const int* edge_index = (const int*)d_in[1];
  const float* W1 = (const float*)d_in[2];
  const float* att_src1 = (const float*)d_in[3];
  const float* att_dst1 = (const float*)d_in[4];
  const float* b1 = (const float*)d_in[5];
  const float* Wp = (const float*)d_in[6];
  const float* bp = (const float*)d_in[7];
  const float* W2 = (const float*)d_in[8];
  const float* att_src2 = (const float*)d_in[9];
  const float* att_dst2 = (const float*)d_in[10];
  const float* b2 = (const float*)d_in[11];
  float* out = (float*)d_out;

  const int N = in_sizes[0] / 768;
  const int E = in_sizes[1] / 2;
  const int Etot = E + N;
  const int* src = edge_index;
  const int* dst = edge_index + E;

  char* ws = (char*)d_ws;
  size_t off = 0;
  auto alloc = [&](size_t bytes) {
    size_t cur = off;
    off += (bytes + 255) & ~(size_t)255;
    return (void*)(ws + cur);
  };
  float* proj = (float*)alloc((size_t)N * 128 * 4);
  unsigned* h1bf = (unsigned*)alloc((size_t)N * 64 * 4);
  float* a_s1 = (float*)alloc((size_t)N * 8 * 4);
  float* a_d1 = (float*)alloc((size_t)N * 8 * 4);
  float* h2 = (float*)alloc((size_t)N * 2 * 4);
  float* as2 = (float*)alloc((size_t)N * 4);
  float* ad2 = (float*)alloc((size_t)N * 4);
  int* counts = (int*)alloc((size_t)N * 4);
  int* offsets = (int*)alloc(((size_t)N + 1) * 4);
  int* rank = (int*)alloc((size_t)E * 4);
  int* bsum = (int*)alloc(256 * 4);
  int* sortedsrc = (int*)alloc((size_t)Etot * 4);
  short* Wt = (short*)alloc((size_t)256 * 768 * 2);

  // 0. weights -> bf16 B^T
  convert_w<<<768, 256, 0, stream>>>(W1, Wp, Wt);
  // 1. MFMA GEMM (emits h1bf + proj)
  gemm_mfma<<<N / 64, 256, 0, stream>>>(x, Wt, proj, h1bf);
  // 2. attention logits from h1bf
  attn1b<<<N * 8 / 256, 256, 0, stream>>>((const uint4*)h1bf, att_src1,
                                          att_dst1, a_s1, a_d1);
  // 3. counting sort by dst (self loop placed in scan_c; rank from hist)
  init_counts<<<(N + 255) / 256, 256, 0, stream>>>(counts, N);
  hist_kernel<<<(E / 4 + 255) / 256, 256, 0, stream>>>(dst, counts, rank, E);
  scan_a<<<N / 256, 256, 0, stream>>>(counts, offsets, bsum);
  scan_b<<<1, 256, 0, stream>>>(bsum);
  scan_c<<<N / 256, 256, 0, stream>>>(offsets, bsum, sortedsrc, N, Etot);
  scatter_edges<<<(E / 4 + 255) / 256, 256, 0, stream>>>(src, dst, rank,
                                                         offsets, sortedsrc, E);
  // 4. layer-1 aggregation + residual + ELU + layer-2 features (fused)
  agg1_fused<<<N / 16, 256, 0, stream>>>((const uint4*)h1bf, proj, a_s1, a_d1,
                                         offsets, sortedsrc, b1, bp, W2,
                                         att_src2, att_dst2, h2, as2, ad2);
  // 5. layer-2 aggregation -> output
  agg2<<<N / 16, 256, 0, stream>>>(h2, as2, ad2, offsets, sortedsrc, b2, out,
                                   N);
}

// Round 6
// 493.391 us; speedup vs baseline: 1.0227x; 1.0152x over previous
//
#include <hip/hip_runtime.h>
#include <hip/hip_bf16.h>
#include <math.h>

#define NEG_SLOPE 0.2f

typedef __attribute__((ext_vector_type(8))) short short8;
typedef __attribute__((ext_vector_type(4))) float float4v;

__device__ __forceinline__ unsigned f2bf(float f) {
  unsigned u = __builtin_bit_cast(unsigned, f);
  return (u + 0x7fffu + ((u >> 16) & 1u)) >> 16;  // RNE
}
__device__ __forceinline__ float bflo(unsigned u) {
  return __builtin_bit_cast(float, u << 16);
}
__device__ __forceinline__ float bfhi(unsigned u) {
  return __builtin_bit_cast(float, u & 0xffff0000u);
}
// packed f32x2 -> bf16x2 (RNE, same rounding as f2bf); gfx950 has no builtin
__device__ __forceinline__ unsigned cvtpk(float lo, float hi) {
  unsigned r;
  asm("v_cvt_pk_bf16_f32 %0, %1, %2" : "=v"(r) : "v"(lo), "v"(hi));
  return r;
}
// async global->LDS DMA, 16B per lane; LDS dest = wave-uniform base + lane*16
__device__ __forceinline__ void gl2lds16(const void* g, void* l) {
  __builtin_amdgcn_global_load_lds(
      (const __attribute__((address_space(1))) unsigned*)g,
      (__attribute__((address_space(3))) unsigned*)l, 16, 0, 0);
}

// ---------------- weight pre-transpose: Wt[c][k] bf16, c in [0,256) --------
__global__ __launch_bounds__(256) void convert_w(const float* __restrict__ W1,
                                                 const float* __restrict__ Wp,
                                                 short* __restrict__ Wt) {
  int k = blockIdx.x;   // 0..767
  int c = threadIdx.x;  // 0..255
  float v = (c < 128) ? W1[k * 128 + c] : Wp[k * 128 + (c - 128)];
  Wt[(size_t)c * 768 + k] = (short)f2bf(v);
}

// ------- bf16 MFMA GEMM: emits h1bf (bf16-packed) + proj (fp32) ------------
// R10: BM=128, BN=256, BK=32, 8 waves (512 thr). Wave (wr,wc)=(w>>2,w&3)
// owns rows wr*64..+63, cols wc*64..+63. wc<2 -> h1 pack; wc>=2 -> proj.
// Rationale: gemm stuck ~118-131us across 4 variants; invariant was 96
// latency-dominated K-steps per CU (4 blocks x 24). This halves steps/CU
// (2 blocks x 24) and doubles MFMA per staged B byte. LDS 48KB (cap 3/CU,
// grid exactly 2/CU -> no tail). Same verified swizzle/fragment mapping.
__global__ __launch_bounds__(512, 4) void gemm_mfma(
    const float* __restrict__ x, const short* __restrict__ Wt,
    float* __restrict__ proj, unsigned* __restrict__ h1bf) {
  __shared__ short As[2][4096];  // [128 rows][32 k] bf16, 16B-slot swizzled
  __shared__ short Bs[2][8192];  // [256 cols][32 k] bf16, 16B-slot swizzled
  const int tid = threadIdx.x;
  const int w = tid >> 6, l = tid & 63;
  const int wr = w >> 2, wc = w & 3;
  const int l15 = l & 15, l4 = l >> 4;
  const int row0 = blockIdx.x * 128;

  // ---- A reg-staging: thread t covers row t>>2 (0..127), k-chunk t&3 -----
  // phys_chunk = chunk ^ ((row>>1)&3)  (2-way max on write & read)
  const float* xsrc = x + (size_t)(row0 + (tid >> 2)) * 768 + (tid & 3) * 8;
  const int awoff = (tid >> 2) * 64 + (((tid & 3) ^ ((tid >> 3) & 3)) << 4);
  // fragment read offset: row wr*64 + rt*16 + l15, logical chunk l4
  const int aoff = (wr * 64 + l15) * 64 + ((l4 ^ ((l15 >> 1) & 3)) << 4);

  // ---- B DMA staging: wave w stages cols w*32..+31 (2 instrs) ------------
  const char* bg[2];
#pragma unroll
  for (int i = 0; i < 2; i++) {
    int c = w * 32 + i * 16 + (l >> 2);
    int q = (l & 3) ^ ((l >> 3) & 3);
    bg[i] = (const char*)Wt + (size_t)c * 1536 + q * 16;
  }
  const int pc = l4 ^ ((l15 >> 1) & 3);  // B physical chunk for this lane

  float4v acc[4][4] = {};

  auto loadA = [&](int t, float4& r0, float4& r1) {
    const float* p = xsrc + t * 32;
    r0 = *(const float4*)p;
    r1 = *(const float4*)(p + 4);
  };
  auto writeA = [&](short* asb, const float4& r0, const float4& r1) {
    uint4 pk;
    pk.x = cvtpk(r0.x, r0.y);
    pk.y = cvtpk(r0.z, r0.w);
    pk.z = cvtpk(r1.x, r1.y);
    pk.w = cvtpk(r1.z, r1.w);
    *(uint4*)((char*)asb + awoff) = pk;
  };
  auto stageB = [&](short* bsb, int t) {
    gl2lds16(bg[0] + t * 64, (char*)bsb + w * 2048 + 0 * 1024);
    gl2lds16(bg[1] + t * 64, (char*)bsb + w * 2048 + 1 * 1024);
  };
  auto compute = [&](const short* asb, const short* bsb) {
    short8 afr[4];
#pragma unroll
    for (int rt = 0; rt < 4; rt++)
      afr[rt] = *(const short8*)((const char*)asb + rt * 1024 + aoff);
#pragma unroll
    for (int ct = 0; ct < 4; ct++) {
      short8 bfr =
          *(const short8*)((const char*)bsb + (wc * 64 + ct * 16 + l15) * 64 + pc * 16);
#pragma unroll
      for (int rt = 0; rt < 4; rt++)
        acc[rt][ct] =
            __builtin_amdgcn_mfma_f32_16x16x32_bf16(afr[rt], bfr, acc[rt][ct], 0, 0, 0);
    }
  };

  float4 r0, r1;
  loadA(0, r0, r1);
  stageB(Bs[0], 0);
  writeA(As[0], r0, r1);
  __syncthreads();  // tile 0 resident (ds_write lgkm + DMA vmcnt drained)
  for (int t = 0; t < 24; t += 2) {
    loadA(t + 1, r0, r1);   // x loads first: cvt waits only on these
    stageB(Bs[1], t + 1);   // B DMA in flight across compute
    compute(As[0], Bs[0]);
    writeA(As[1], r0, r1);
    __syncthreads();  // tile t+1 resident; buf0 reads done
    if (t + 2 < 24) {
      loadA(t + 2, r0, r1);
      stageB(Bs[0], t + 2);
    }
    compute(As[1], Bs[1]);
    if (t + 2 < 24) writeA(As[0], r0, r1);
    __syncthreads();  // tile t+2 resident; buf1 reads done
  }

  if (wc < 2) {
    // h1 columns (0..127) -> packed bf16 (pair channels via 1 shuffle)
#pragma unroll
    for (int ct = 0; ct < 4; ct++) {
      const int c = wc * 64 + ct * 16 + l15;
#pragma unroll
      for (int rt = 0; rt < 4; rt++) {
#pragma unroll
        for (int r = 0; r < 4; r++) {
          const int R = row0 + wr * 64 + rt * 16 + l4 * 4 + r;
          unsigned u = f2bf(acc[rt][ct][r]);
          unsigned up = __shfl_xor(u, 1);
          if ((l15 & 1) == 0) h1bf[(size_t)R * 64 + (c >> 1)] = u | (up << 16);
        }
      }
    }
  } else {
    // proj columns (0..127)
#pragma unroll
    for (int ct = 0; ct < 4; ct++) {
      const int c = (wc - 2) * 64 + ct * 16 + l15;
#pragma unroll
      for (int rt = 0; rt < 4; rt++) {
#pragma unroll
        for (int r = 0; r < 4; r++) {
          const int R = row0 + wr * 64 + rt * 16 + l4 * 4 + r;
          proj[(size_t)R * 128 + c] = acc[rt][ct][r];
        }
      }
    }
  }
}

// ---------------- attention logits from h1bf (thread per node,head) --------
__global__ __launch_bounds__(256) void attn1b(const uint4* __restrict__ h1bf4,
                                              const float* __restrict__ att_src1,
                                              const float* __restrict__ att_dst1,
                                              float* __restrict__ a_s1,
                                              float* __restrict__ a_d1) {
  const int t = blockIdx.x * 256 + threadIdx.x;  // t in [0, N*8)
  const int n = t >> 3, h = t & 7;
  uint4 q0 = h1bf4[(size_t)n * 16 + h * 2];
  uint4 q1 = h1bf4[(size_t)n * 16 + h * 2 + 1];
  float v[16];
  v[0] = bflo(q0.x); v[1] = bfhi(q0.x); v[2] = bflo(q0.y); v[3] = bfhi(q0.y);
  v[4] = bflo(q0.z); v[5] = bfhi(q0.z); v[6] = bflo(q0.w); v[7] = bfhi(q0.w);
  v[8] = bflo(q1.x); v[9] = bfhi(q1.x); v[10] = bflo(q1.y); v[11] = bfhi(q1.y);
  v[12] = bflo(q1.z); v[13] = bfhi(q1.z); v[14] = bflo(q1.w); v[15] = bfhi(q1.w);
  float as = 0.f, ad = 0.f;
#pragma unroll
  for (int i = 0; i < 16; i++) {
    as += v[i] * att_src1[h * 16 + i];
    ad += v[i] * att_dst1[h * 16 + i];
  }
  a_s1[t] = as;
  a_d1[t] = ad;
}

// ---------------- counting sort of edges by dst ----------------------------
__global__ void init_counts(int* counts, int N) {
  int i = blockIdx.x * blockDim.x + threadIdx.x;
  if (i < N) counts[i] = 1;  // self loop
}

// rank = atomicAdd return (was previously discarded) so scatter needs no atomics
__global__ void hist_kernel(const int* __restrict__ dst, int* counts,
                            int* __restrict__ rank, int E) {
  int i = blockIdx.x * blockDim.x + threadIdx.x;
  int base = i * 4;
  if (base + 3 < E) {
    int4 d = *(const int4*)&dst[base];
    int4 r;
    r.x = atomicAdd(&counts[d.x], 1);
    r.y = atomicAdd(&counts[d.y], 1);
    r.z = atomicAdd(&counts[d.z], 1);
    r.w = atomicAdd(&counts[d.w], 1);
    *(int4*)&rank[base] = r;
  } else {
    for (int j = base; j < E; j++) rank[j] = atomicAdd(&counts[dst[j]], 1);
  }
}

__global__ __launch_bounds__(256) void scan_a(const int* __restrict__ counts,
                                              int* offsets, int* bsum) {
  __shared__ int s[256];
  int t = threadIdx.x, idx = blockIdx.x * 256 + t;
  int v = counts[idx];
  s[t] = v;
  __syncthreads();
  for (int d = 1; d < 256; d <<= 1) {
    int x = (t >= d) ? s[t - d] : 0;
    __syncthreads();
    s[t] += x;
    __syncthreads();
  }
  offsets[idx] = s[t] - v;
  if (t == 255) bsum[blockIdx.x] = s[t];
}

__global__ __launch_bounds__(256) void scan_b(int* bsum) {
  __shared__ int s[256];
  int t = threadIdx.x;
  int v = bsum[t];
  s[t] = v;
  __syncthreads();
  for (int d = 1; d < 256; d <<= 1) {
    int x = (t >= d) ? s[t - d] : 0;
    __syncthreads();
    s[t] += x;
    __syncthreads();
  }
  bsum[t] = s[t] - v;
}

// also places the self-loop at segment start
__global__ __launch_bounds__(256) void scan_c(int* offsets, const int* bsum,
                                              int* sortedsrc, int N, int Etot) {
  int t = threadIdx.x, idx = blockIdx.x * 256 + t;
  int off = offsets[idx] + bsum[blockIdx.x];
  offsets[idx] = off;
  sortedsrc[off] = idx;  // self loop at slot 0 (ranks from hist start at 1)
  if (idx == 0) offsets[N] = Etot;
}

// atomic-free scatter — slot = offsets[dst] + rank (rank >= 1).
__global__ void scatter_edges(const int* __restrict__ src,
                              const int* __restrict__ dst,
                              const int* __restrict__ rank,
                              const int* __restrict__ offsets,
                              int* __restrict__ sortedsrc, int E) {
  int i = blockIdx.x * blockDim.x + threadIdx.x;
  int base = i * 4;
  if (base + 3 < E) {
    int4 s = *(const int4*)&src[base];
    int4 d = *(const int4*)&dst[base];
    int4 r = *(const int4*)&rank[base];
    sortedsrc[offsets[d.x] + r.x] = s.x;
    sortedsrc[offsets[d.y] + r.y] = s.y;
    sortedsrc[offsets[d.z] + r.z] = s.z;
    sortedsrc[offsets[d.w] + r.w] = s.w;
  } else {
    for (int j = base; j < E; j++)
      sortedsrc[offsets[dst[j]] + rank[j]] = src[j];
  }
}

// ------- layer-1 aggregation + residual + ELU + layer-2 features -----------
// 16 nodes/block (256 thr), 16 lanes/node, 8 channels/lane (uint4 gathers),
// 4-deep edge pipeline. R10: emits packed rec[n]={h2x,h2y,as2,ad2} so agg2
// does ONE 16B gather per edge.
__global__ __launch_bounds__(256) void agg1_fused(
    const uint4* __restrict__ h1bf4, const float* __restrict__ proj,
    const float* __restrict__ a_s1, const float* __restrict__ a_d1,
    const int* __restrict__ offsets, const int* __restrict__ sortedsrc,
    const float* __restrict__ b1, const float* __restrict__ bp,
    const float* __restrict__ W2, const float* __restrict__ att_s2,
    const float* __restrict__ att_d2, float4* __restrict__ rec) {
  const int t = threadIdx.x;
  const int n = blockIdx.x * 16 + (t >> 4);
  const int k = t & 15;   // lane within node: channels 8k..8k+7
  const int hd = k >> 1;  // head
  const float ad = a_d1[n * 8 + hd];
  const int begin = offsets[n], end = offsets[n + 1];
  float acc[8] = {};
  float aw = 0.f;
  int j = begin;
  for (; j + 4 <= end; j += 4) {
    int s0 = sortedsrc[j], s1 = sortedsrc[j + 1];
    int s2 = sortedsrc[j + 2], s3 = sortedsrc[j + 3];
    float e0 = a_s1[s0 * 8 + hd], e1 = a_s1[s1 * 8 + hd];
    float e2 = a_s1[s2 * 8 + hd], e3 = a_s1[s3 * 8 + hd];
    uint4 q0 = h1bf4[(size_t)s0 * 16 + k];
    uint4 q1 = h1bf4[(size_t)s1 * 16 + k];
    uint4 q2 = h1bf4[(size_t)s2 * 16 + k];
    uint4 q3 = h1bf4[(size_t)s3 * 16 + k];
    e0 += ad; e1 += ad; e2 += ad; e3 += ad;
    float w0 = __expf(e0 > 0.f ? e0 : NEG_SLOPE * e0);
    float w1 = __expf(e1 > 0.f ? e1 : NEG_SLOPE * e1);
    float w2 = __expf(e2 > 0.f ? e2 : NEG_SLOPE * e2);
    float w3 = __expf(e3 > 0.f ? e3 : NEG_SLOPE * e3);
    acc[0] += w0 * bflo(q0.x) + w1 * bflo(q1.x) + w2 * bflo(q2.x) + w3 * bflo(q3.x);
    acc[1] += w0 * bfhi(q0.x) + w1 * bfhi(q1.x) + w2 * bfhi(q2.x) + w3 * bfhi(q3.x);
    acc[2] += w0 * bflo(q0.y) + w1 * bflo(q1.y) + w2 * bflo(q2.y) + w3 * bflo(q3.y);
    acc[3] += w0 * bfhi(q0.y) + w1 * bfhi(q1.y) + w2 * bfhi(q2.y) + w3 * bfhi(q3.y);
    acc[4] += w0 * bflo(q0.z) + w1 * bflo(q1.z) + w2 * bflo(q2.z) + w3 * bflo(q3.z);
    acc[5] += w0 * bfhi(q0.z) + w1 * bfhi(q1.z) + w2 * bfhi(q2.z) + w3 * bfhi(q3.z);
    acc[6] += w0 * bflo(q0.w) + w1 * bflo(q1.w) + w2 * bflo(q2.w) + w3 * bflo(q3.w);
    acc[7] += w0 * bfhi(q0.w) + w1 * bfhi(q1.w) + w2 * bfhi(q2.w) + w3 * bfhi(q3.w);
    aw += (w0 + w1) + (w2 + w3);
  }
  for (; j < end; j++) {
    int s0 = sortedsrc[j];
    float e0 = a_s1[s0 * 8 + hd] + ad;
    uint4 q0 = h1bf4[(size_t)s0 * 16 + k];
    float w0 = __expf(e0 > 0.f ? e0 : NEG_SLOPE * e0);
    acc[0] += w0 * bflo(q0.x);
    acc[1] += w0 * bfhi(q0.x);
    acc[2] += w0 * bflo(q0.y);
    acc[3] += w0 * bfhi(q0.y);
    acc[4] += w0 * bflo(q0.z);
    acc[5] += w0 * bfhi(q0.z);
    acc[6] += w0 * bflo(q0.w);
    acc[7] += w0 * bfhi(q0.w);
    aw += w0;
  }
  const float inv = 1.f / (aw + 1e-16f);
  const float4 pj0 = *(const float4*)&proj[(size_t)n * 128 + k * 8];
  const float4 pj1 = *(const float4*)&proj[(size_t)n * 128 + k * 8 + 4];
  const float4 b1a = *(const float4*)&b1[k * 8];
  const float4 b1b = *(const float4*)&b1[k * 8 + 4];
  const float4 bpa = *(const float4*)&bp[k * 8];
  const float4 bpb = *(const float4*)&bp[k * 8 + 4];
  float v[8];
  v[0] = acc[0] * inv + pj0.x + b1a.x + bpa.x;
  v[1] = acc[1] * inv + pj0.y + b1a.y + bpa.y;
  v[2] = acc[2] * inv + pj0.z + b1a.z + bpa.z;
  v[3] = acc[3] * inv + pj0.w + b1a.w + bpa.w;
  v[4] = acc[4] * inv + pj1.x + b1b.x + bpb.x;
  v[5] = acc[5] * inv + pj1.y + b1b.y + bpb.y;
  v[6] = acc[6] * inv + pj1.z + b1b.z + bpb.z;
  v[7] = acc[7] * inv + pj1.w + b1b.w + bpb.w;
  float p0 = 0.f, p1 = 0.f;
#pragma unroll
  for (int i = 0; i < 8; i++) {
    float vi = v[i] > 0.f ? v[i] : (__expf(v[i]) - 1.f);
    float2 w2 = *(const float2*)&W2[(k * 8 + i) * 2];
    p0 += vi * w2.x;
    p1 += vi * w2.y;
  }
#pragma unroll
  for (int off = 8; off; off >>= 1) {
    p0 += __shfl_xor(p0, off);
    p1 += __shfl_xor(p1, off);
  }
  if (k == 0) {
    float as = p0 * att_s2[0] + p1 * att_s2[1];
    float adv = p0 * att_d2[0] + p1 * att_d2[1];
    rec[n] = make_float4(p0, p1, as, adv);
  }
}

// ---------------- layer-2 aggregation (16 lanes per node) ------------------
// R10: single 16B rec gather per edge (was 4B as2 + 8B h2).
__global__ __launch_bounds__(256) void agg2(
    const float4* __restrict__ rec, const int* __restrict__ offsets,
    const int* __restrict__ sortedsrc, const float* __restrict__ b2,
    float* __restrict__ out, int N) {
  const int node = blockIdx.x * 16 + (threadIdx.x >> 4);
  const int lane = threadIdx.x & 15;
  const int begin = offsets[node], end = offsets[node + 1];
  const float ad = rec[node].w;
  float acc0 = 0.f, acc1 = 0.f, aw = 0.f;
  for (int j = begin + lane; j < end; j += 16) {
    int s = sortedsrc[j];
    float4 rs = rec[s];
    float e = rs.z + ad;
    float w = __expf(e > 0.f ? e : NEG_SLOPE * e);
    acc0 += w * rs.x;
    acc1 += w * rs.y;
    aw += w;
  }
#pragma unroll
  for (int off = 8; off; off >>= 1) {
    acc0 += __shfl_xor(acc0, off);
    acc1 += __shfl_xor(acc1, off);
    aw += __shfl_xor(aw, off);
  }
  if (lane == 0) {
    float inv = 1.f / (aw + 1e-16f);
    out[2 * node] = acc0 * inv + b2[0];
    out[2 * node + 1] = acc1 * inv + b2[1];
  }
}

extern "C" void kernel_launch(void* const* d_in, const int* in_sizes, int n_in,
                              void* d_out, int out_size, void* d_ws,
                              size_t ws_size, hipStream_t stream) {
  const float* x = (const float*)d_in[0];
  const int* edge_index = (const int*)d_in[1];
  const float* W1 = (const float*)d_in[2];
  const float* att_src1 = (const float*)d_in[3];
  const float* att_dst1 = (const float*)d_in[4];
  const float* b1 = (const float*)d_in[5];
  const float* Wp = (const float*)d_in[6];
  const float* bp = (const float*)d_in[7];
  const float* W2 = (const float*)d_in[8];
  const float* att_src2 = (const float*)d_in[9];
  const float* att_dst2 = (const float*)d_in[10];
  const float* b2 = (const float*)d_in[11];
  float* out = (float*)d_out;

  const int N = in_sizes[0] / 768;
  const int E = in_sizes[1] / 2;
  const int Etot = E + N;
  const int* src = edge_index;
  const int* dst = edge_index + E;

  char* ws = (char*)d_ws;
  size_t off = 0;
  auto alloc = [&](size_t bytes) {
    size_t cur = off;
    off += (bytes + 255) & ~(size_t)255;
    return (void*)(ws + cur);
  };
  float* proj = (float*)alloc((size_t)N * 128 * 4);
  unsigned* h1bf = (unsigned*)alloc((size_t)N * 64 * 4);
  float* a_s1 = (float*)alloc((size_t)N * 8 * 4);
  float* a_d1 = (float*)alloc((size_t)N * 8 * 4);
  float4* rec = (float4*)alloc((size_t)N * 16);
  int* counts = (int*)alloc((size_t)N * 4);
  int* offsets = (int*)alloc(((size_t)N + 1) * 4);
  int* rank = (int*)alloc((size_t)E * 4);
  int* bsum = (int*)alloc(256 * 4);
  int* sortedsrc = (int*)alloc((size_t)Etot * 4);
  short* Wt = (short*)alloc((size_t)256 * 768 * 2);

  // 0. weights -> bf16 B^T
  convert_w<<<768, 256, 0, stream>>>(W1, Wp, Wt);
  // 1. MFMA GEMM (emits h1bf + proj)
  gemm_mfma<<<N / 128, 512, 0, stream>>>(x, Wt, proj, h1bf);
  // 2. attention logits from h1bf
  attn1b<<<N * 8 / 256, 256, 0, stream>>>((const uint4*)h1bf, att_src1,
                                          att_dst1, a_s1, a_d1);
  // 3. counting sort by dst (self loop placed in scan_c; rank from hist)
  init_counts<<<(N + 255) / 256, 256, 0, stream>>>(counts, N);
  hist_kernel<<<(E / 4 + 255) / 256, 256, 0, stream>>>(dst, counts, rank, E);
  scan_a<<<N / 256, 256, 0, stream>>>(counts, offsets, bsum);
  scan_b<<<1, 256, 0, stream>>>(bsum);
  scan_c<<<N / 256, 256, 0, stream>>>(offsets, bsum, sortedsrc, N, Etot);
  scatter_edges<<<(E / 4 + 255) / 256, 256, 0, stream>>>(src, dst, rank,
                                                         offsets, sortedsrc, E);
  // 4. layer-1 aggregation + residual + ELU + layer-2 features (fused)
  agg1_fused<<<N / 16, 256, 0, stream>>>((const uint4*)h1bf, proj, a_s1, a_d1,
                                         offsets, sortedsrc, b1, bp, W2,
                                         att_src2, att_dst2, rec);
  // 5. layer-2 aggregation -> output
  agg2<<<N / 16, 256, 0, stream>>>(rec, offsets, sortedsrc, b2, out, N);
}